// Round 22
// baseline (338.648 us; speedup 1.0000x reference)
//
#include <hip/hip_runtime.h>

#define BB 4
#define DD 4096
#define FF 128
#define SLOPE 0.2f

typedef float f32x4 __attribute__((ext_vector_type(4)));
typedef int   i32x4 __attribute__((ext_vector_type(4)));
typedef short bf16x8 __attribute__((ext_vector_type(8)));

// LDS-only barrier: ds_writes visible across waves, but global loads/stores
// stay in flight (no vmcnt drain, unlike __syncthreads()).
#define SOFT_BARRIER() do { \
  asm volatile("s_waitcnt lgkmcnt(0)" ::: "memory"); \
  __builtin_amdgcn_s_barrier(); \
} while (0)

__device__ __forceinline__ unsigned short f2bf(float v) {
  union { float f; unsigned u; } c; c.f = v;
  unsigned r = c.u + 0x7FFFu + ((c.u >> 16) & 1u);
  return (unsigned short)(r >> 16);
}

// Kernel A: Wh = x@W (f32 regs) -> WhT bf16 [B][F][D]; fs, ft (f32);
// mbpart[wg] = max(0, max over this wg's 64 rows of ft)  (no memset needed)
__global__ __launch_bounds__(256) void kA(
    const float* __restrict__ x, const float* __restrict__ W,
    const float* __restrict__ a_src, const float* __restrict__ a_tgt,
    unsigned short* __restrict__ WhT, float* __restrict__ fs,
    float* __restrict__ ft, float* __restrict__ mbpart)
{
  __shared__ __align__(16) float Ws[128 * 128];
  __shared__ __align__(16) float xs[64 * 128];     // reused as reduction scratch
  __shared__ unsigned short st[128 * 66];
  const int t = threadIdx.x;
  const int wg = blockIdx.x;            // 256 wgs x 64 rows
  const int row0 = wg * 64;             // flat row in [0, B*D)
  const int b = row0 / DD;
  const int i_in_b = row0 % DD;

  for (int i = t * 4; i < 128 * 128; i += 1024)
    *(float4*)&Ws[i] = *(const float4*)&W[i];
  for (int i = t * 4; i < 64 * 128; i += 1024)
    *(float4*)&xs[i] = *(const float4*)&x[(size_t)row0 * FF + i];
  __syncthreads();

  const int fg = t & 31, rg = t >> 5;
  const int f0 = fg * 4, r0 = rg * 8;
  float acc[8][4];
  #pragma unroll
  for (int a = 0; a < 8; ++a) acc[a][0] = acc[a][1] = acc[a][2] = acc[a][3] = 0.f;
  for (int k = 0; k < 128; ++k) {
    float4 wq = *(const float4*)&Ws[k * 128 + f0];
    #pragma unroll
    for (int rr = 0; rr < 8; ++rr) {
      float xv = xs[(r0 + rr) * 128 + k];
      acc[rr][0] += xv * wq.x; acc[rr][1] += xv * wq.y;
      acc[rr][2] += xv * wq.z; acc[rr][3] += xv * wq.w;
    }
  }
  __syncthreads();   // done reading xs; reuse as reduction scratch
  float* red_s = xs;             // [64][33]
  float* red_t = xs + 64 * 33;   // [64][33]
  float4 as4 = *(const float4*)&a_src[f0];
  float4 at4 = *(const float4*)&a_tgt[f0];
  #pragma unroll
  for (int rr = 0; rr < 8; ++rr) {
    float ps = acc[rr][0]*as4.x + acc[rr][1]*as4.y + acc[rr][2]*as4.z + acc[rr][3]*as4.w;
    float pt = acc[rr][0]*at4.x + acc[rr][1]*at4.y + acc[rr][2]*at4.z + acc[rr][3]*at4.w;
    red_s[(r0 + rr) * 33 + fg] = ps;
    red_t[(r0 + rr) * 33 + fg] = pt;
    st[(f0 + 0) * 66 + r0 + rr] = f2bf(acc[rr][0]);
    st[(f0 + 1) * 66 + r0 + rr] = f2bf(acc[rr][1]);
    st[(f0 + 2) * 66 + r0 + rr] = f2bf(acc[rr][2]);
    st[(f0 + 3) * 66 + r0 + rr] = f2bf(acc[rr][3]);
  }
  __syncthreads();
  if (t < 64) {
    float s = 0.f, tt = 0.f;
    #pragma unroll
    for (int q = 0; q < 32; ++q) { s += red_s[t * 33 + q]; tt += red_t[t * 33 + q]; }
    fs[row0 + t] = s;
    ft[row0 + t] = tt;
    float m = fmaxf(0.f, tt);
    #pragma unroll
    for (int s2 = 1; s2 < 64; s2 <<= 1) m = fmaxf(m, __shfl_xor(m, s2));
    if (t == 0) mbpart[wg] = m;        // unconditional write: no init required
  }
  // WhT bf16 writeout (coalesced per 64-wide row chunks)
  for (int p = 0; p < 32; ++p) {
    int idx = p * 256 + t;
    int f = idx >> 6, rl = idx & 63;
    WhT[((size_t)b * FF + f) * DD + i_in_b + rl] = st[f * 66 + rl];
  }
}

// Kernel P1: one wave per row, pure streaming, no LDS/barriers.
// Streams adj once (the ONLY full adj read) -> bitmask [row][128 words] +
// rowsum of exp(e - M).
__global__ __launch_bounds__(256) void kP1(
    const int* __restrict__ adj, const float* __restrict__ fs,
    const float* __restrict__ ft, const float* __restrict__ mbpart,
    unsigned int* __restrict__ maskw, float* __restrict__ sums)
{
  const int t = threadIdx.x;
  const int wv = t >> 6, l = t & 63;
  const int row = blockIdx.x * 4 + wv;       // flat row in [0, B*D)
  const int b = row >> 12;
  float mbv = mbpart[b * 64 + l];
  #pragma unroll
  for (int s = 1; s < 64; s <<= 1) mbv = fmaxf(mbv, __shfl_xor(mbv, s));
  const float fsr = fs[row];
  const float M = fmaxf(0.f, fsr + mbv);
  const int* arow = adj + (size_t)row * DD + l * 64;
  const float* ftl = ft + (size_t)b * DD + l * 64;
  float sum = 0.f;
  unsigned wlo = 0u, whi = 0u;
  #pragma unroll
  for (int q = 0; q < 4; ++q) {
    unsigned bits = 0u;
    #pragma unroll
    for (int u = 0; u < 4; ++u) {
      const int o = q * 16 + u * 4;
      i32x4 a = *(const i32x4*)(arow + o);
      float4 f = *(const float4*)(ftl + o);
      float e0 = fsr + f.x; e0 = fmaxf(e0, SLOPE * e0); e0 = a.x ? e0 : 0.f;
      float e1 = fsr + f.y; e1 = fmaxf(e1, SLOPE * e1); e1 = a.y ? e1 : 0.f;
      float e2 = fsr + f.z; e2 = fmaxf(e2, SLOPE * e2); e2 = a.z ? e2 : 0.f;
      float e3 = fsr + f.w; e3 = fmaxf(e3, SLOPE * e3); e3 = a.w ? e3 : 0.f;
      sum += __expf(e0 - M) + __expf(e1 - M) + __expf(e2 - M) + __expf(e3 - M);
      bits |= (a.x ? 1u : 0u) << (u * 4 + 0);
      bits |= (a.y ? 1u : 0u) << (u * 4 + 1);
      bits |= (a.z ? 1u : 0u) << (u * 4 + 2);
      bits |= (a.w ? 1u : 0u) << (u * 4 + 3);
    }
    if      (q == 0) wlo  = bits;
    else if (q == 1) wlo |= bits << 16;
    else if (q == 2) whi  = bits;
    else             whi |= bits << 16;
  }
  uint2 mv; mv.x = wlo; mv.y = whi;
  *(uint2*)(maskw + (size_t)row * 128 + l * 2) = mv;
  #pragma unroll
  for (int s = 1; s < 64; s <<= 1) sum += __shfl_xor(sum, s);
  if (l == 0) sums[row] = sum;
}

// Kernel F2 (column-split): 512 wgs x (64 rows x 2048 cols), 8 waves,
// LDS = 64KB p_lds + 16KB mlds = 80KB -> 2 wg/CU. No adj stream (masks from
// kP1). Champion chunk pipeline (8 chunks of 256 cols), B-reuse x4 preserved.
// h' partials: jh=0 -> hraw (hout region, raw), jh=1 -> hpart (ws); kC adds.
__global__ __launch_bounds__(512, 4) void kF2(
    const unsigned int* __restrict__ maskw, const float* __restrict__ fs,
    const float* __restrict__ ft, const float* __restrict__ mbpart,
    const float* __restrict__ sums, const unsigned short* __restrict__ WhT,
    float* __restrict__ hraw, float* __restrict__ hpart,
    float* __restrict__ attn)
{
  __shared__ __align__(16) unsigned short p_lds[2][64 * 256];  // 64 KB, XOR-swizzled
  __shared__ __align__(16) unsigned int mlds[64 * 64];         // 16 KB half-row masks
  const int t = threadIdx.x;
  const int w = t >> 6, l = t & 63;
  const int hw = blockIdx.x;
  const int bid = (hw & 7) * 64 + (hw >> 3);   // bijective XCD swizzle (nwg=512)
  const int b = bid >> 7;
  const int rem = bid & 127;
  const int i0 = (rem >> 1) << 6;              // 64 rows per wg
  const int jh = rem & 1;
  const int j0 = jh << 11;                     // column half base (0 or 2048)
  // stage this half's masks: thread t loads 8 words for row t>>3
  {
    const int r = t >> 3, wq = (t & 7) * 8;
    const unsigned int* src = maskw + (size_t)(b * DD + i0 + r) * 128 + jh * 64 + wq;
    *(uint4*)&mlds[r * 64 + wq]     = *(const uint4*)src;
    *(uint4*)&mlds[r * 64 + wq + 4] = *(const uint4*)(src + 4);
  }
  float mbv = mbpart[b * 64 + l];
  #pragma unroll
  for (int s = 1; s < 64; s <<= 1) mbv = fmaxf(mbv, __shfl_xor(mbv, s));
  const int rbase = 8 * w;                     // wave owns rows rbase..rbase+7
  float fsr[8], Mr[8], inv[8];
  #pragma unroll
  for (int m = 0; m < 8; ++m) {
    fsr[m] = fs[b * DD + i0 + rbase + m];
    Mr[m] = fmaxf(0.f, fsr[m] + mbv);
    inv[m] = 1.0f / sums[b * DD + i0 + rbase + m];
  }

  const float* ftb = ft + (size_t)b * DD + j0;
  const int jl = l * 4;
  const unsigned mshift = (unsigned)(jl & 31);
  float* arow[8];
  unsigned o_[8], wb_[8];
  #pragma unroll
  for (int m = 0; m < 8; ++m) {
    const int r = rbase + m;
    arow[m] = attn + (size_t)b * DD * DD + (size_t)(i0 + r) * DD + j0;
    o_[m] = (((unsigned)r * 512u) + (unsigned)jl * 2u) ^ ((unsigned)(r & 7) << 4);
    wb_[m] = (unsigned)r * 64u + (unsigned)(jl >> 5);
  }
  const int f0 = w * 16;
  const int c15 = l & 15;
  const int kg = l >> 4;
  const unsigned abase = (unsigned)c15 * 512u + (unsigned)kg * 16u;
  const unsigned asw = (unsigned)(c15 & 7) << 4;
  const unsigned short* wrow = WhT + ((size_t)b * FF + f0 + c15) * DD + j0 + kg * 8;
  f32x4 acc[4];
  #pragma unroll
  for (int q = 0; q < 4; ++q) acc[q] = (f32x4){0.f, 0.f, 0.f, 0.f};

  bf16x8 BvA[8], BvB[8];
  float4 fA, fB;
  #pragma unroll
  for (int u = 0; u < 8; ++u)
    BvA[u] = *(const bf16x8*)&wrow[(size_t)u * 32];
  fA = *(const float4*)(ftb + jl);
  SOFT_BARRIER();   // mlds staging visible to all waves

#define CHUNK_BODY(CC, BCUR, BNXT, FCUR, FNXT) do { \
    const int c_ = (CC); \
    const int j_ = c_ * 256 + jl; \
    /* issue next chunk's B and ft early: in flight across soft barrier */ \
    _Pragma("unroll") \
    for (int u = 0; u < 8; ++u) \
      BNXT[u] = *(const bf16x8*)&wrow[(size_t)((((c_) + 1) & 7) * 8 + u) * 32]; \
    FNXT = *(const float4*)(ftb + ((((c_) + 1) & 7) * 256 + jl)); \
    float4 f4_ = FCUR; \
    f32x4 v_[8]; \
    _Pragma("unroll") \
    for (int m = 0; m < 8; ++m) { \
      unsigned n_ = (mlds[wb_[m] + (unsigned)c_ * 8u] >> mshift) & 0xFu; \
      float e_, p0_, p1_, p2_, p3_; \
      e_ = fsr[m] + f4_.x; e_ = fmaxf(e_, SLOPE * e_); e_ = (n_ & 1u) ? e_ : 0.f; p0_ = __expf(e_ - Mr[m]) * inv[m]; \
      e_ = fsr[m] + f4_.y; e_ = fmaxf(e_, SLOPE * e_); e_ = (n_ & 2u) ? e_ : 0.f; p1_ = __expf(e_ - Mr[m]) * inv[m]; \
      e_ = fsr[m] + f4_.z; e_ = fmaxf(e_, SLOPE * e_); e_ = (n_ & 4u) ? e_ : 0.f; p2_ = __expf(e_ - Mr[m]) * inv[m]; \
      e_ = fsr[m] + f4_.w; e_ = fmaxf(e_, SLOPE * e_); e_ = (n_ & 8u) ? e_ : 0.f; p3_ = __expf(e_ - Mr[m]) * inv[m]; \
      v_[m].x = p0_; v_[m].y = p1_; v_[m].z = p2_; v_[m].w = p3_; \
      ushort4 qv_; qv_.x = f2bf(p0_); qv_.y = f2bf(p1_); qv_.z = f2bf(p2_); qv_.w = f2bf(p3_); \
      *(ushort4*)((char*)&p_lds[c_ & 1][0] + o_[m]) = qv_; \
    } \
    SOFT_BARRIER(); \
    /* attn stores AFTER barrier: off the gating path, overlap MFMA */ \
    _Pragma("unroll") \
    for (int m = 0; m < 8; ++m) \
      *(f32x4*)(arow[m] + j_) = v_[m]; \
    __builtin_amdgcn_s_setprio(1); \
    _Pragma("unroll") \
    for (int u = 0; u < 8; ++u) { \
      unsigned ao_ = (abase + (unsigned)u * 64u) ^ asw; \
      _Pragma("unroll") \
      for (int T = 0; T < 4; ++T) { \
        bf16x8 A_ = *(const bf16x8*)((const char*)&p_lds[c_ & 1][0] + ao_ + (unsigned)T * 8192u); \
        acc[T] = __builtin_amdgcn_mfma_f32_16x16x32_bf16(A_, BCUR[u], acc[T], 0, 0, 0); \
      } \
    } \
    __builtin_amdgcn_s_setprio(0); \
  } while (0)

  for (int cc = 0; cc < 4; ++cc) {
    CHUNK_BODY(cc * 2,     BvA, BvB, fA, fB);
    CHUNK_BODY(cc * 2 + 1, BvB, BvA, fB, fA);
  }
#undef CHUNK_BODY

  // partial h' (no bias): jh=0 -> hraw (hout region), jh=1 -> hpart (ws)
  float* outp = jh ? hpart : hraw;
  #pragma unroll
  for (int T = 0; T < 4; ++T) {
    #pragma unroll
    for (int q = 0; q < 4; ++q) {
      int orow = T * 16 + kg * 4 + q;   // C/D: row = (lane>>4)*4 + reg
      outp[((size_t)b * DD + i0 + orow) * FF + f0 + c15] = acc[T][q];
    }
  }
}

// Kernel C: hout = hraw + hpart + bias  (24 MB traffic)
__global__ __launch_bounds__(256) void kC(
    float* __restrict__ hout, const float* __restrict__ hpart,
    const float* __restrict__ bias)
{
  const int idx = blockIdx.x * 256 + threadIdx.x;   // f32x4 granularity
  f32x4 a = *(const f32x4*)&hout[(size_t)idx * 4];
  f32x4 p = *(const f32x4*)&hpart[(size_t)idx * 4];
  float4 bv = *(const float4*)&bias[(idx * 4) & 127];
  f32x4 r;
  r.x = a.x + p.x + bv.x; r.y = a.y + p.y + bv.y;
  r.z = a.z + p.z + bv.z; r.w = a.w + p.w + bv.w;
  *(f32x4*)&hout[(size_t)idx * 4] = r;
}

extern "C" void kernel_launch(void* const* d_in, const int* in_sizes, int n_in,
                              void* d_out, int out_size, void* d_ws, size_t ws_size,
                              hipStream_t stream) {
  const float* x     = (const float*)d_in[0];
  const int*   adj   = (const int*)d_in[1];
  const float* W     = (const float*)d_in[2];
  const float* a_src = (const float*)d_in[3];
  const float* a_tgt = (const float*)d_in[4];
  const float* bias  = (const float*)d_in[5];
  char* ws = (char*)d_ws;
  unsigned short* WhT    = (unsigned short*)ws;          // 4 MB
  float*        fs     = (float*)(ws + 4194304);         // 64 KB
  float*        ft     = (float*)(ws + 4259840);         // 64 KB
  float*        mbpart = (float*)(ws + 4325376);         // 1 KB
  unsigned int* maskw  = (unsigned int*)(ws + 4456448);  // 8 MB
  float*        sums   = (float*)(ws + 12845056);        // 64 KB
  float*        hpart  = (float*)(ws + 12910592);        // 8 MB
  float* hout = (float*)d_out;                           // [B][D][F]
  float* attn = hout + (size_t)BB * DD * FF;             // [B][D][D]
  kA<<<256, 256, 0, stream>>>(x, W, a_src, a_tgt, WhT, fs, ft, mbpart);
  kP1<<<BB * DD / 4, 256, 0, stream>>>(adj, fs, ft, mbpart, maskw, sums);
  kF2<<<512, 512, 0, stream>>>(maskw, fs, ft, mbpart, sums, WhT, hout, hpart, attn);
  kC<<<BB * DD * FF / 1024, 256, 0, stream>>>(hout, hpart, bias);
}

// Round 23
// 211.098 us; speedup vs baseline: 1.6042x; 1.6042x over previous
//
#include <hip/hip_runtime.h>

#define BB 4
#define DD 4096
#define FF 128
#define SLOPE 0.2f

typedef float f32x4 __attribute__((ext_vector_type(4)));
typedef int   i32x4 __attribute__((ext_vector_type(4)));
typedef short bf16x8 __attribute__((ext_vector_type(8)));

// LDS-only barrier: ds_writes visible across waves, but global loads/stores
// stay in flight (no vmcnt drain, unlike __syncthreads()).
#define SOFT_BARRIER() do { \
  asm volatile("s_waitcnt lgkmcnt(0)" ::: "memory"); \
  __builtin_amdgcn_s_barrier(); \
} while (0)

__device__ __forceinline__ unsigned short f2bf(float v) {
  union { float f; unsigned u; } c; c.f = v;
  unsigned r = c.u + 0x7FFFu + ((c.u >> 16) & 1u);
  return (unsigned short)(r >> 16);
}

// Kernel A: Wh = x@W (f32 regs) -> WhT bf16 [B][F][D]; fs, ft (f32);
// mbpart[wg] = max(0, max over this wg's 64 rows of ft)  (no memset needed)
__global__ __launch_bounds__(256) void kA(
    const float* __restrict__ x, const float* __restrict__ W,
    const float* __restrict__ a_src, const float* __restrict__ a_tgt,
    unsigned short* __restrict__ WhT, float* __restrict__ fs,
    float* __restrict__ ft, float* __restrict__ mbpart)
{
  __shared__ __align__(16) float Ws[128 * 128];
  __shared__ __align__(16) float xs[64 * 128];     // reused as reduction scratch
  __shared__ unsigned short st[128 * 66];
  const int t = threadIdx.x;
  const int wg = blockIdx.x;            // 256 wgs x 64 rows
  const int row0 = wg * 64;             // flat row in [0, B*D)
  const int b = row0 / DD;
  const int i_in_b = row0 % DD;

  for (int i = t * 4; i < 128 * 128; i += 1024)
    *(float4*)&Ws[i] = *(const float4*)&W[i];
  for (int i = t * 4; i < 64 * 128; i += 1024)
    *(float4*)&xs[i] = *(const float4*)&x[(size_t)row0 * FF + i];
  __syncthreads();

  const int fg = t & 31, rg = t >> 5;
  const int f0 = fg * 4, r0 = rg * 8;
  float acc[8][4];
  #pragma unroll
  for (int a = 0; a < 8; ++a) acc[a][0] = acc[a][1] = acc[a][2] = acc[a][3] = 0.f;
  for (int k = 0; k < 128; ++k) {
    float4 wq = *(const float4*)&Ws[k * 128 + f0];
    #pragma unroll
    for (int rr = 0; rr < 8; ++rr) {
      float xv = xs[(r0 + rr) * 128 + k];
      acc[rr][0] += xv * wq.x; acc[rr][1] += xv * wq.y;
      acc[rr][2] += xv * wq.z; acc[rr][3] += xv * wq.w;
    }
  }
  __syncthreads();   // done reading xs; reuse as reduction scratch
  float* red_s = xs;             // [64][33]
  float* red_t = xs + 64 * 33;   // [64][33]
  float4 as4 = *(const float4*)&a_src[f0];
  float4 at4 = *(const float4*)&a_tgt[f0];
  #pragma unroll
  for (int rr = 0; rr < 8; ++rr) {
    float ps = acc[rr][0]*as4.x + acc[rr][1]*as4.y + acc[rr][2]*as4.z + acc[rr][3]*as4.w;
    float pt = acc[rr][0]*at4.x + acc[rr][1]*at4.y + acc[rr][2]*at4.z + acc[rr][3]*at4.w;
    red_s[(r0 + rr) * 33 + fg] = ps;
    red_t[(r0 + rr) * 33 + fg] = pt;
    st[(f0 + 0) * 66 + r0 + rr] = f2bf(acc[rr][0]);
    st[(f0 + 1) * 66 + r0 + rr] = f2bf(acc[rr][1]);
    st[(f0 + 2) * 66 + r0 + rr] = f2bf(acc[rr][2]);
    st[(f0 + 3) * 66 + r0 + rr] = f2bf(acc[rr][3]);
  }
  __syncthreads();
  if (t < 64) {
    float s = 0.f, tt = 0.f;
    #pragma unroll
    for (int q = 0; q < 32; ++q) { s += red_s[t * 33 + q]; tt += red_t[t * 33 + q]; }
    fs[row0 + t] = s;
    ft[row0 + t] = tt;
    float m = fmaxf(0.f, tt);
    #pragma unroll
    for (int s2 = 1; s2 < 64; s2 <<= 1) m = fmaxf(m, __shfl_xor(m, s2));
    if (t == 0) mbpart[wg] = m;        // unconditional write: no init required
  }
  // WhT bf16 writeout (coalesced per 64-wide row chunks)
  for (int p = 0; p < 32; ++p) {
    int idx = p * 256 + t;
    int f = idx >> 6, rl = idx & 63;
    WhT[((size_t)b * FF + f) * DD + i_in_b + rl] = st[f * 66 + rl];
  }
}

// Kernel P1: one wave per row, pure streaming, no LDS/barriers.
// Streams adj once (the ONLY full adj read) -> bitmask [row][128 words] +
// rowsum of exp(e - M).
__global__ __launch_bounds__(256) void kP1(
    const int* __restrict__ adj, const float* __restrict__ fs,
    const float* __restrict__ ft, const float* __restrict__ mbpart,
    unsigned int* __restrict__ maskw, float* __restrict__ sums)
{
  const int t = threadIdx.x;
  const int wv = t >> 6, l = t & 63;
  const int row = blockIdx.x * 4 + wv;       // flat row in [0, B*D)
  const int b = row >> 12;
  float mbv = mbpart[b * 64 + l];
  #pragma unroll
  for (int s = 1; s < 64; s <<= 1) mbv = fmaxf(mbv, __shfl_xor(mbv, s));
  const float fsr = fs[row];
  const float M = fmaxf(0.f, fsr + mbv);
  const int* arow = adj + (size_t)row * DD + l * 64;
  const float* ftl = ft + (size_t)b * DD + l * 64;
  float sum = 0.f;
  unsigned wlo = 0u, whi = 0u;
  #pragma unroll
  for (int q = 0; q < 4; ++q) {
    unsigned bits = 0u;
    #pragma unroll
    for (int u = 0; u < 4; ++u) {
      const int o = q * 16 + u * 4;
      i32x4 a = *(const i32x4*)(arow + o);
      float4 f = *(const float4*)(ftl + o);
      float e0 = fsr + f.x; e0 = fmaxf(e0, SLOPE * e0); e0 = a.x ? e0 : 0.f;
      float e1 = fsr + f.y; e1 = fmaxf(e1, SLOPE * e1); e1 = a.y ? e1 : 0.f;
      float e2 = fsr + f.z; e2 = fmaxf(e2, SLOPE * e2); e2 = a.z ? e2 : 0.f;
      float e3 = fsr + f.w; e3 = fmaxf(e3, SLOPE * e3); e3 = a.w ? e3 : 0.f;
      sum += __expf(e0 - M) + __expf(e1 - M) + __expf(e2 - M) + __expf(e3 - M);
      bits |= (a.x ? 1u : 0u) << (u * 4 + 0);
      bits |= (a.y ? 1u : 0u) << (u * 4 + 1);
      bits |= (a.z ? 1u : 0u) << (u * 4 + 2);
      bits |= (a.w ? 1u : 0u) << (u * 4 + 3);
    }
    if      (q == 0) wlo  = bits;
    else if (q == 1) wlo |= bits << 16;
    else if (q == 2) whi  = bits;
    else             whi |= bits << 16;
  }
  uint2 mv; mv.x = wlo; mv.y = whi;
  *(uint2*)(maskw + (size_t)row * 128 + l * 2) = mv;
  #pragma unroll
  for (int s = 1; s < 64; s <<= 1) sum += __shfl_xor(sum, s);
  if (l == 0) sums[row] = sum;
}

// Kernel F2 (column-split): 512 wgs x (64 rows x 2048 cols), 8 waves,
// LDS = 64KB p_lds + 16KB mlds = 80KB -> 2 wg/CU. No adj stream (masks from
// kP1). Champion chunk pipeline (8 chunks of 256 cols), B-reuse x4 preserved.
// launch_bounds (512,2): VGPR cap 256, compiler lands ~128 -> NO SPILLS
// (R22's (512,4) forced VGPR=64 -> 440 MB scratch traffic).
__global__ __launch_bounds__(512, 2) void kF2(
    const unsigned int* __restrict__ maskw, const float* __restrict__ fs,
    const float* __restrict__ ft, const float* __restrict__ mbpart,
    const float* __restrict__ sums, const unsigned short* __restrict__ WhT,
    float* __restrict__ hraw, float* __restrict__ hpart,
    float* __restrict__ attn)
{
  __shared__ __align__(16) unsigned short p_lds[2][64 * 256];  // 64 KB, XOR-swizzled
  __shared__ __align__(16) unsigned int mlds[64 * 64];         // 16 KB half-row masks
  const int t = threadIdx.x;
  const int w = t >> 6, l = t & 63;
  const int hw = blockIdx.x;
  const int bid = (hw & 7) * 64 + (hw >> 3);   // bijective XCD swizzle (nwg=512)
  const int b = bid >> 7;
  const int rem = bid & 127;
  const int i0 = (rem >> 1) << 6;              // 64 rows per wg
  const int jh = rem & 1;
  const int j0 = jh << 11;                     // column half base (0 or 2048)
  // stage this half's masks: thread t loads 8 words for row t>>3
  {
    const int r = t >> 3, wq = (t & 7) * 8;
    const unsigned int* src = maskw + (size_t)(b * DD + i0 + r) * 128 + jh * 64 + wq;
    *(uint4*)&mlds[r * 64 + wq]     = *(const uint4*)src;
    *(uint4*)&mlds[r * 64 + wq + 4] = *(const uint4*)(src + 4);
  }
  float mbv = mbpart[b * 64 + l];
  #pragma unroll
  for (int s = 1; s < 64; s <<= 1) mbv = fmaxf(mbv, __shfl_xor(mbv, s));
  const int rbase = 8 * w;                     // wave owns rows rbase..rbase+7
  float fsr[8], Mr[8], inv[8];
  #pragma unroll
  for (int m = 0; m < 8; ++m) {
    fsr[m] = fs[b * DD + i0 + rbase + m];
    Mr[m] = fmaxf(0.f, fsr[m] + mbv);
    inv[m] = 1.0f / sums[b * DD + i0 + rbase + m];
  }

  const float* ftb = ft + (size_t)b * DD + j0;
  const int jl = l * 4;
  const unsigned mshift = (unsigned)(jl & 31);
  float* arow[8];
  unsigned o_[8], wb_[8];
  #pragma unroll
  for (int m = 0; m < 8; ++m) {
    const int r = rbase + m;
    arow[m] = attn + (size_t)b * DD * DD + (size_t)(i0 + r) * DD + j0;
    o_[m] = (((unsigned)r * 512u) + (unsigned)jl * 2u) ^ ((unsigned)(r & 7) << 4);
    wb_[m] = (unsigned)r * 64u + (unsigned)(jl >> 5);
  }
  const int f0 = w * 16;
  const int c15 = l & 15;
  const int kg = l >> 4;
  const unsigned abase = (unsigned)c15 * 512u + (unsigned)kg * 16u;
  const unsigned asw = (unsigned)(c15 & 7) << 4;
  const unsigned short* wrow = WhT + ((size_t)b * FF + f0 + c15) * DD + j0 + kg * 8;
  f32x4 acc[4];
  #pragma unroll
  for (int q = 0; q < 4; ++q) acc[q] = (f32x4){0.f, 0.f, 0.f, 0.f};

  bf16x8 BvA[8], BvB[8];
  float4 fA, fB;
  #pragma unroll
  for (int u = 0; u < 8; ++u)
    BvA[u] = *(const bf16x8*)&wrow[(size_t)u * 32];
  fA = *(const float4*)(ftb + jl);
  SOFT_BARRIER();   // mlds staging visible to all waves

#define CHUNK_BODY(CC, BCUR, BNXT, FCUR, FNXT) do { \
    const int c_ = (CC); \
    const int j_ = c_ * 256 + jl; \
    /* issue next chunk's B and ft early: in flight across soft barrier */ \
    _Pragma("unroll") \
    for (int u = 0; u < 8; ++u) \
      BNXT[u] = *(const bf16x8*)&wrow[(size_t)((((c_) + 1) & 7) * 8 + u) * 32]; \
    FNXT = *(const float4*)(ftb + ((((c_) + 1) & 7) * 256 + jl)); \
    float4 f4_ = FCUR; \
    f32x4 v_[8]; \
    _Pragma("unroll") \
    for (int m = 0; m < 8; ++m) { \
      unsigned n_ = (mlds[wb_[m] + (unsigned)c_ * 8u] >> mshift) & 0xFu; \
      float e_, p0_, p1_, p2_, p3_; \
      e_ = fsr[m] + f4_.x; e_ = fmaxf(e_, SLOPE * e_); e_ = (n_ & 1u) ? e_ : 0.f; p0_ = __expf(e_ - Mr[m]) * inv[m]; \
      e_ = fsr[m] + f4_.y; e_ = fmaxf(e_, SLOPE * e_); e_ = (n_ & 2u) ? e_ : 0.f; p1_ = __expf(e_ - Mr[m]) * inv[m]; \
      e_ = fsr[m] + f4_.z; e_ = fmaxf(e_, SLOPE * e_); e_ = (n_ & 4u) ? e_ : 0.f; p2_ = __expf(e_ - Mr[m]) * inv[m]; \
      e_ = fsr[m] + f4_.w; e_ = fmaxf(e_, SLOPE * e_); e_ = (n_ & 8u) ? e_ : 0.f; p3_ = __expf(e_ - Mr[m]) * inv[m]; \
      v_[m].x = p0_; v_[m].y = p1_; v_[m].z = p2_; v_[m].w = p3_; \
      ushort4 qv_; qv_.x = f2bf(p0_); qv_.y = f2bf(p1_); qv_.z = f2bf(p2_); qv_.w = f2bf(p3_); \
      *(ushort4*)((char*)&p_lds[c_ & 1][0] + o_[m]) = qv_; \
    } \
    SOFT_BARRIER(); \
    /* attn stores AFTER barrier: off the gating path, overlap MFMA */ \
    _Pragma("unroll") \
    for (int m = 0; m < 8; ++m) \
      *(f32x4*)(arow[m] + j_) = v_[m]; \
    __builtin_amdgcn_s_setprio(1); \
    _Pragma("unroll") \
    for (int u = 0; u < 8; ++u) { \
      unsigned ao_ = (abase + (unsigned)u * 64u) ^ asw; \
      _Pragma("unroll") \
      for (int T = 0; T < 4; ++T) { \
        bf16x8 A_ = *(const bf16x8*)((const char*)&p_lds[c_ & 1][0] + ao_ + (unsigned)T * 8192u); \
        acc[T] = __builtin_amdgcn_mfma_f32_16x16x32_bf16(A_, BCUR[u], acc[T], 0, 0, 0); \
      } \
    } \
    __builtin_amdgcn_s_setprio(0); \
  } while (0)

  for (int cc = 0; cc < 4; ++cc) {
    CHUNK_BODY(cc * 2,     BvA, BvB, fA, fB);
    CHUNK_BODY(cc * 2 + 1, BvB, BvA, fB, fA);
  }
#undef CHUNK_BODY

  // partial h' (no bias): jh=0 -> hraw (hout region), jh=1 -> hpart (ws)
  float* outp = jh ? hpart : hraw;
  #pragma unroll
  for (int T = 0; T < 4; ++T) {
    #pragma unroll
    for (int q = 0; q < 4; ++q) {
      int orow = T * 16 + kg * 4 + q;   // C/D: row = (lane>>4)*4 + reg
      outp[((size_t)b * DD + i0 + orow) * FF + f0 + c15] = acc[T][q];
    }
  }
}

// Kernel C: hout = hraw + hpart + bias  (24 MB traffic)
__global__ __launch_bounds__(256) void kC(
    float* __restrict__ hout, const float* __restrict__ hpart,
    const float* __restrict__ bias)
{
  const int idx = blockIdx.x * 256 + threadIdx.x;   // f32x4 granularity
  f32x4 a = *(const f32x4*)&hout[(size_t)idx * 4];
  f32x4 p = *(const f32x4*)&hpart[(size_t)idx * 4];
  float4 bv = *(const float4*)&bias[(idx * 4) & 127];
  f32x4 r;
  r.x = a.x + p.x + bv.x; r.y = a.y + p.y + bv.y;
  r.z = a.z + p.z + bv.z; r.w = a.w + p.w + bv.w;
  *(f32x4*)&hout[(size_t)idx * 4] = r;
}

extern "C" void kernel_launch(void* const* d_in, const int* in_sizes, int n_in,
                              void* d_out, int out_size, void* d_ws, size_t ws_size,
                              hipStream_t stream) {
  const float* x     = (const float*)d_in[0];
  const int*   adj   = (const int*)d_in[1];
  const float* W     = (const float*)d_in[2];
  const float* a_src = (const float*)d_in[3];
  const float* a_tgt = (const float*)d_in[4];
  const float* bias  = (const float*)d_in[5];
  char* ws = (char*)d_ws;
  unsigned short* WhT    = (unsigned short*)ws;          // 4 MB
  float*        fs     = (float*)(ws + 4194304);         // 64 KB
  float*        ft     = (float*)(ws + 4259840);         // 64 KB
  float*        mbpart = (float*)(ws + 4325376);         // 1 KB
  unsigned int* maskw  = (unsigned int*)(ws + 4456448);  // 8 MB
  float*        sums   = (float*)(ws + 12845056);        // 64 KB
  float*        hpart  = (float*)(ws + 12910592);        // 8 MB
  float* hout = (float*)d_out;                           // [B][D][F]
  float* attn = hout + (size_t)BB * DD * FF;             // [B][D][D]
  kA<<<256, 256, 0, stream>>>(x, W, a_src, a_tgt, WhT, fs, ft, mbpart);
  kP1<<<BB * DD / 4, 256, 0, stream>>>(adj, fs, ft, mbpart, maskw, sums);
  kF2<<<512, 512, 0, stream>>>(maskw, fs, ft, mbpart, sums, WhT, hout, hpart, attn);
  kC<<<BB * DD * FF / 1024, 256, 0, stream>>>(hout, hpart, bias);
}

// Round 24
// 200.012 us; speedup vs baseline: 1.6931x; 1.0554x over previous
//
#include <hip/hip_runtime.h>

#define BB 4
#define DD 4096
#define FF 128
#define SLOPE 0.2f

typedef float f32x4 __attribute__((ext_vector_type(4)));
typedef int   i32x4 __attribute__((ext_vector_type(4)));
typedef short bf16x8 __attribute__((ext_vector_type(8)));

// LDS-only barrier: ds_writes visible across waves, but global loads/stores
// stay in flight (no vmcnt drain, unlike __syncthreads()).
#define SOFT_BARRIER() do { \
  asm volatile("s_waitcnt lgkmcnt(0)" ::: "memory"); \
  __builtin_amdgcn_s_barrier(); \
} while (0)

__device__ __forceinline__ unsigned short f2bf(float v) {
  union { float f; unsigned u; } c; c.f = v;
  unsigned r = c.u + 0x7FFFu + ((c.u >> 16) & 1u);
  return (unsigned short)(r >> 16);
}

// Kernel A: Wh = x@W (f32 regs) -> WhT bf16 [B][F][D]; fs, ft (f32);
// mbpart[wg] = max(0, max over this wg's 64 rows of ft)  (no memset needed)
__global__ __launch_bounds__(256) void kA(
    const float* __restrict__ x, const float* __restrict__ W,
    const float* __restrict__ a_src, const float* __restrict__ a_tgt,
    unsigned short* __restrict__ WhT, float* __restrict__ fs,
    float* __restrict__ ft, float* __restrict__ mbpart)
{
  __shared__ __align__(16) float Ws[128 * 128];
  __shared__ __align__(16) float xs[64 * 128];     // reused as reduction scratch
  __shared__ unsigned short st[128 * 66];
  const int t = threadIdx.x;
  const int wg = blockIdx.x;            // 256 wgs x 64 rows
  const int row0 = wg * 64;             // flat row in [0, B*D)
  const int b = row0 / DD;
  const int i_in_b = row0 % DD;

  for (int i = t * 4; i < 128 * 128; i += 1024)
    *(float4*)&Ws[i] = *(const float4*)&W[i];
  for (int i = t * 4; i < 64 * 128; i += 1024)
    *(float4*)&xs[i] = *(const float4*)&x[(size_t)row0 * FF + i];
  __syncthreads();

  const int fg = t & 31, rg = t >> 5;
  const int f0 = fg * 4, r0 = rg * 8;
  float acc[8][4];
  #pragma unroll
  for (int a = 0; a < 8; ++a) acc[a][0] = acc[a][1] = acc[a][2] = acc[a][3] = 0.f;
  for (int k = 0; k < 128; ++k) {
    float4 wq = *(const float4*)&Ws[k * 128 + f0];
    #pragma unroll
    for (int rr = 0; rr < 8; ++rr) {
      float xv = xs[(r0 + rr) * 128 + k];
      acc[rr][0] += xv * wq.x; acc[rr][1] += xv * wq.y;
      acc[rr][2] += xv * wq.z; acc[rr][3] += xv * wq.w;
    }
  }
  __syncthreads();   // done reading xs; reuse as reduction scratch
  float* red_s = xs;             // [64][33]
  float* red_t = xs + 64 * 33;   // [64][33]
  float4 as4 = *(const float4*)&a_src[f0];
  float4 at4 = *(const float4*)&a_tgt[f0];
  #pragma unroll
  for (int rr = 0; rr < 8; ++rr) {
    float ps = acc[rr][0]*as4.x + acc[rr][1]*as4.y + acc[rr][2]*as4.z + acc[rr][3]*as4.w;
    float pt = acc[rr][0]*at4.x + acc[rr][1]*at4.y + acc[rr][2]*at4.z + acc[rr][3]*at4.w;
    red_s[(r0 + rr) * 33 + fg] = ps;
    red_t[(r0 + rr) * 33 + fg] = pt;
    st[(f0 + 0) * 66 + r0 + rr] = f2bf(acc[rr][0]);
    st[(f0 + 1) * 66 + r0 + rr] = f2bf(acc[rr][1]);
    st[(f0 + 2) * 66 + r0 + rr] = f2bf(acc[rr][2]);
    st[(f0 + 3) * 66 + r0 + rr] = f2bf(acc[rr][3]);
  }
  __syncthreads();
  if (t < 64) {
    float s = 0.f, tt = 0.f;
    #pragma unroll
    for (int q = 0; q < 32; ++q) { s += red_s[t * 33 + q]; tt += red_t[t * 33 + q]; }
    fs[row0 + t] = s;
    ft[row0 + t] = tt;
    float m = fmaxf(0.f, tt);
    #pragma unroll
    for (int s2 = 1; s2 < 64; s2 <<= 1) m = fmaxf(m, __shfl_xor(m, s2));
    if (t == 0) mbpart[wg] = m;        // unconditional write: no init required
  }
  // WhT bf16 writeout (coalesced per 64-wide row chunks)
  for (int p = 0; p < 32; ++p) {
    int idx = p * 256 + t;
    int f = idx >> 6, rl = idx & 63;
    WhT[((size_t)b * FF + f) * DD + i_in_b + rl] = st[f * 66 + rl];
  }
}

// Kernel F (fused): R10 structure (64 rows/wg, 8 waves, 256 wgs,
// 16-chunk pipeline, B/ft double-buffer, soft barrier) + 3 micro-opts:
//  (1) leaky_relu via fmaxf(e, SLOPE*e)   — fewer VALU on exp path
//  (2) attn stores AFTER the barrier      — off the barrier-gating path,
//      overlap the MFMA section (v_[8] f32x4 live across barrier)
//  (3) s_setprio(1) around MFMA cluster   — favor MFMA-phase waves
__global__ __launch_bounds__(512, 2) void kF(
    const int* __restrict__ adj, const float* __restrict__ fs,
    const float* __restrict__ ft, const float* __restrict__ mbpart,
    const unsigned short* __restrict__ WhT, const float* __restrict__ bias,
    float* __restrict__ hout, float* __restrict__ attn)
{
  __shared__ __align__(16) unsigned short p_lds[2][64 * 256];  // 64 KB, XOR-swizzled
  __shared__ __align__(16) unsigned int mlds[64 * 128];        // 32 KB row bitmasks
  const int t = threadIdx.x;
  const int w = t >> 6, l = t & 63;
  const int hw = blockIdx.x;
  const int bid = (hw & 7) * 32 + (hw >> 3);   // bijective XCD swizzle (nwg=256)
  const int b = bid >> 6;
  const int i0 = (bid & 63) << 6;              // 64 rows per wg
  // per-batch ft upper bound from kA partials
  float mbv = mbpart[b * 64 + l];
  #pragma unroll
  for (int s = 1; s < 64; s <<= 1) mbv = fmaxf(mbv, __shfl_xor(mbv, s));
  const int rbase = 8 * w;                     // wave owns rows rbase..rbase+7
  float fsr[8], Mr[8];
  #pragma unroll
  for (int m = 0; m < 8; ++m) {
    fsr[m] = fs[b * DD + i0 + rbase + m];
    Mr[m] = fmaxf(0.f, fsr[m] + mbv);
  }

  // ---- Pass 1: stream 8 adj rows in two 4-row groups, 2-deep pipelined ----
  const float* ftl = ft + (size_t)b * DD + l * 64;
  float sum[8];
  float inv[8];
  #pragma unroll
  for (int m = 0; m < 8; ++m) sum[m] = 0.f;

  #pragma unroll
  for (int g = 0; g < 2; ++g) {
    const int mb0 = g * 4;
    const int* ap[4];
    #pragma unroll
    for (int m = 0; m < 4; ++m)
      ap[m] = adj + (size_t)(b * DD + i0 + rbase + mb0 + m) * DD + l * 64;
    unsigned lo[4] = {0u, 0u, 0u, 0u}, hi[4] = {0u, 0u, 0u, 0u};

    auto p1_load = [&](i32x4 (&buf)[4][2], int q) {
      #pragma unroll
      for (int m = 0; m < 4; ++m) {
        buf[m][0] = *(const i32x4*)(ap[m] + q * 8);
        buf[m][1] = *(const i32x4*)(ap[m] + q * 8 + 4);
      }
    };
    auto p1_cons = [&](i32x4 (&buf)[4][2], int q) {
      #pragma unroll
      for (int u = 0; u < 2; ++u) {
        const int o = q * 8 + u * 4;
        float4 f = *(const float4*)(ftl + o);
        #pragma unroll
        for (int m = 0; m < 4; ++m) {
          i32x4 a = buf[m][u];
          float e;
          e = fsr[mb0+m] + f.x; e = fmaxf(e, SLOPE * e); e = a.x ? e : 0.f; sum[mb0+m] += __expf(e - Mr[mb0+m]);
          e = fsr[mb0+m] + f.y; e = fmaxf(e, SLOPE * e); e = a.y ? e : 0.f; sum[mb0+m] += __expf(e - Mr[mb0+m]);
          e = fsr[mb0+m] + f.z; e = fmaxf(e, SLOPE * e); e = a.z ? e : 0.f; sum[mb0+m] += __expf(e - Mr[mb0+m]);
          e = fsr[mb0+m] + f.w; e = fmaxf(e, SLOPE * e); e = a.w ? e : 0.f; sum[mb0+m] += __expf(e - Mr[mb0+m]);
          unsigned pack = (a.x ? 1u : 0u) | (a.y ? 2u : 0u) | (a.z ? 4u : 0u) | (a.w ? 8u : 0u);
          if (o < 32) lo[m] |= pack << o; else hi[m] |= pack << (o - 32);
        }
      }
    };

    i32x4 bA[4][2], bB[4][2];
    p1_load(bA, 0);
    p1_load(bB, 1);
    #pragma unroll
    for (int q = 0; q < 8; q += 2) {
      p1_cons(bA, q);
      if (q + 2 < 8) p1_load(bA, q + 2);
      p1_cons(bB, q + 1);
      if (q + 3 < 8) p1_load(bB, q + 3);
    }
    #pragma unroll
    for (int m = 0; m < 4; ++m) {
      uint2 mv; mv.x = lo[m]; mv.y = hi[m];
      *(uint2*)&mlds[(rbase + mb0 + m) * 128 + l * 2] = mv;
    }
  }
  #pragma unroll
  for (int m = 0; m < 8; ++m) {
    #pragma unroll
    for (int s = 1; s < 64; s <<= 1) sum[m] += __shfl_xor(sum[m], s);
    inv[m] = 1.0f / sum[m];
  }

  // ---- Pass 2: 16-chunk pipeline (soft barriers, B/ft double-buffered) ----
  const float* ftb = ft + (size_t)b * DD;
  float* arow[8];
  unsigned o_[8], wb_[8];
  const int jl = l * 4;
  const unsigned mshift = (unsigned)(jl & 31);
  #pragma unroll
  for (int m = 0; m < 8; ++m) {
    const int r = rbase + m;
    arow[m] = attn + (size_t)b * DD * DD + (size_t)(i0 + r) * DD;
    o_[m] = (((unsigned)r * 512u) + (unsigned)jl * 2u) ^ ((unsigned)(r & 7) << 4);
    wb_[m] = (unsigned)r * 128u + (unsigned)(jl >> 5);
  }
  const int f0 = w * 16;
  const int c15 = l & 15;
  const int kg = l >> 4;
  const unsigned abase = (unsigned)c15 * 512u + (unsigned)kg * 16u;
  const unsigned asw = (unsigned)(c15 & 7) << 4;
  const unsigned short* wrow = WhT + ((size_t)b * FF + f0 + c15) * DD + kg * 8;
  f32x4 acc[4];
  #pragma unroll
  for (int q = 0; q < 4; ++q) acc[q] = (f32x4){0.f, 0.f, 0.f, 0.f};

  bf16x8 BvA[8], BvB[8];
  float4 fA, fB;
  #pragma unroll
  for (int u = 0; u < 8; ++u)
    BvA[u] = *(const bf16x8*)&wrow[(size_t)u * 32];
  fA = *(const float4*)(ftb + jl);

#define CHUNK_BODY(CC, BCUR, BNXT, FCUR, FNXT) do { \
    const int c_ = (CC); \
    const int j_ = c_ * 256 + jl; \
    /* issue next chunk's B and ft early: in flight across soft barrier */ \
    _Pragma("unroll") \
    for (int u = 0; u < 8; ++u) \
      BNXT[u] = *(const bf16x8*)&wrow[(size_t)((((c_) + 1) & 15) * 8 + u) * 32]; \
    FNXT = *(const float4*)(ftb + ((((c_) + 1) & 15) * 256 + jl)); \
    float4 f4_ = FCUR; \
    f32x4 v_[8]; \
    _Pragma("unroll") \
    for (int m = 0; m < 8; ++m) { \
      unsigned n_ = (mlds[wb_[m] + (unsigned)c_ * 8u] >> mshift) & 0xFu; \
      float e_, p0_, p1_, p2_, p3_; \
      e_ = fsr[m] + f4_.x; e_ = fmaxf(e_, SLOPE * e_); e_ = (n_ & 1u) ? e_ : 0.f; p0_ = __expf(e_ - Mr[m]) * inv[m]; \
      e_ = fsr[m] + f4_.y; e_ = fmaxf(e_, SLOPE * e_); e_ = (n_ & 2u) ? e_ : 0.f; p1_ = __expf(e_ - Mr[m]) * inv[m]; \
      e_ = fsr[m] + f4_.z; e_ = fmaxf(e_, SLOPE * e_); e_ = (n_ & 4u) ? e_ : 0.f; p2_ = __expf(e_ - Mr[m]) * inv[m]; \
      e_ = fsr[m] + f4_.w; e_ = fmaxf(e_, SLOPE * e_); e_ = (n_ & 8u) ? e_ : 0.f; p3_ = __expf(e_ - Mr[m]) * inv[m]; \
      v_[m].x = p0_; v_[m].y = p1_; v_[m].z = p2_; v_[m].w = p3_; \
      ushort4 qv_; qv_.x = f2bf(p0_); qv_.y = f2bf(p1_); qv_.z = f2bf(p2_); qv_.w = f2bf(p3_); \
      *(ushort4*)((char*)&p_lds[c_ & 1][0] + o_[m]) = qv_; \
    } \
    SOFT_BARRIER(); \
    /* attn stores AFTER barrier: off the gating path, overlap MFMA */ \
    _Pragma("unroll") \
    for (int m = 0; m < 8; ++m) \
      *(f32x4*)(arow[m] + j_) = v_[m]; \
    __builtin_amdgcn_s_setprio(1); \
    _Pragma("unroll") \
    for (int u = 0; u < 8; ++u) { \
      unsigned ao_ = (abase + (unsigned)u * 64u) ^ asw; \
      _Pragma("unroll") \
      for (int T = 0; T < 4; ++T) { \
        bf16x8 A_ = *(const bf16x8*)((const char*)&p_lds[c_ & 1][0] + ao_ + (unsigned)T * 8192u); \
        acc[T] = __builtin_amdgcn_mfma_f32_16x16x32_bf16(A_, BCUR[u], acc[T], 0, 0, 0); \
      } \
    } \
    __builtin_amdgcn_s_setprio(0); \
  } while (0)

  for (int cc = 0; cc < 8; ++cc) {
    CHUNK_BODY(cc * 2,     BvA, BvB, fA, fB);
    CHUNK_BODY(cc * 2 + 1, BvB, BvA, fB, fA);
  }
#undef CHUNK_BODY

  const float bv = bias[f0 + c15];
  #pragma unroll
  for (int T = 0; T < 4; ++T) {
    #pragma unroll
    for (int q = 0; q < 4; ++q) {
      int orow = T * 16 + kg * 4 + q;   // C/D: row = (lane>>4)*4 + reg
      hout[((size_t)b * DD + i0 + orow) * FF + f0 + c15] = acc[T][q] + bv;
    }
  }
}

extern "C" void kernel_launch(void* const* d_in, const int* in_sizes, int n_in,
                              void* d_out, int out_size, void* d_ws, size_t ws_size,
                              hipStream_t stream) {
  const float* x     = (const float*)d_in[0];
  const int*   adj   = (const int*)d_in[1];
  const float* W     = (const float*)d_in[2];
  const float* a_src = (const float*)d_in[3];
  const float* a_tgt = (const float*)d_in[4];
  const float* bias  = (const float*)d_in[5];
  char* ws = (char*)d_ws;
  unsigned short* WhT    = (unsigned short*)ws;         // 4 MB
  float*        fs     = (float*)(ws + 4194304);        // 64 KB
  float*        ft     = (float*)(ws + 4259840);        // 64 KB
  float*        mbpart = (float*)(ws + 4325376);        // 1 KB
  float* hout = (float*)d_out;                          // [B][D][F]
  float* attn = hout + (size_t)BB * DD * FF;            // [B][D][D]
  kA<<<256, 256, 0, stream>>>(x, W, a_src, a_tgt, WhT, fs, ft, mbpart);
  kF<<<256, 512, 0, stream>>>(adj, fs, ft, mbpart, WhT, bias, hout, attn);
}